// Round 11
// baseline (57.904 us; speedup 1.0000x reference)
//
#include <hip/hip_runtime.h>
#include <stdint.h>

#define KDIM 2048
#define NEXP 64
#define MT   64              // tokens per block
#define KC   32              // k per chunk
#define NCH  (KDIM / KC)     // 64 chunks
#define NTHR 256             // 4 waves: 2 token-halves x 2 expert-halves

#define GLOBAL_AS __attribute__((address_space(1)))
#define LDS_AS    __attribute__((address_space(3)))

typedef _Float16 half8 __attribute__((ext_vector_type(8)));
typedef __fp16  fp16x2 __attribute__((ext_vector_type(2)));
typedef float f32x4 __attribute__((ext_vector_type(4)));

__device__ __forceinline__ uint32_t pkrtz(float a, float b) {
    fp16x2 h = __builtin_amdgcn_cvt_pkrtz(a, b);
    return __builtin_bit_cast(uint32_t, h);
}

struct HL { half8 h; half8 l; };

// split 8 f32 into f16 hi (exact mantissa-truncate) + f16 lo (rtz residual)
__device__ __forceinline__ HL split8(float4 a, float4 b) {
    float y[8] = {a.x, a.y, a.z, a.w, b.x, b.y, b.z, b.w};
    uint32_t hw[4], lw[4];
    #pragma unroll
    for (int i = 0; i < 4; ++i) {
        float y0 = y[2 * i], y1 = y[2 * i + 1];
        float h0 = __builtin_bit_cast(float, __builtin_bit_cast(uint32_t, y0) & 0xFFFFE000u);
        float h1 = __builtin_bit_cast(float, __builtin_bit_cast(uint32_t, y1) & 0xFFFFE000u);
        hw[i] = pkrtz(h0, h1);
        lw[i] = pkrtz(y0 - h0, y1 - h1);
    }
    HL r;
    uint4 hv = {hw[0], hw[1], hw[2], hw[3]};
    uint4 lv = {lw[0], lw[1], lw[2], lw[3]};
    r.h = __builtin_bit_cast(half8, hv);
    r.l = __builtin_bit_cast(half8, lv);
    return r;
}

// W[64][2048] f32 -> per-chunk (KC=32) fragment-ordered slabs of 8 KB:
// slab c: hi plane [g][lane][j] (2048 halfs) then lo plane (+2048 halfs)
// maps to W_pl[e = g*16+(lane&15)][k = c*32 + (lane>>4)*8 + j]
__global__ __launch_bounds__(256) void prep_w(const float* __restrict__ W,
                                              _Float16* __restrict__ Bf) {
    int idx  = blockIdx.x * 256 + threadIdx.x;   // 16384 threads = (c,g,lane)
    int lane = idx & 63;
    int g    = (idx >> 6) & 3;
    int c    = idx >> 8;
    int e = g * 16 + (lane & 15);
    int k = c * 32 + ((lane >> 4) << 3);
    const float4* src = reinterpret_cast<const float4*>(W + (size_t)e * KDIM + k);
    HL r = split8(src[0], src[1]);
    size_t base = (size_t)c * 4096 + ((size_t)(g * 64 + lane)) * 8;
    *reinterpret_cast<half8*>(Bf + base) = r.h;
    *reinterpret_cast<half8*>(Bf + base + 2048) = r.l;
}

// counted waits + raw barrier: loads stay in flight across barriers (AITER pattern)
#define VMW12() do { asm volatile("s_waitcnt vmcnt(12)" ::: "memory"); \
                     __builtin_amdgcn_sched_barrier(0); } while (0)
#define VMW6()  do { asm volatile("s_waitcnt vmcnt(6)"  ::: "memory"); \
                     __builtin_amdgcn_sched_barrier(0); } while (0)
#define VMW0()  do { asm volatile("s_waitcnt vmcnt(0)"  ::: "memory"); \
                     __builtin_amdgcn_sched_barrier(0); } while (0)
#define SBAR()  do { asm volatile("s_waitcnt lgkmcnt(0)" ::: "memory"); \
                     __builtin_amdgcn_sched_barrier(0);                 \
                     __builtin_amdgcn_s_barrier();                      \
                     __builtin_amdgcn_sched_barrier(0); } while (0)

__global__ __launch_bounds__(NTHR, 1) void router_kernel(const float* __restrict__ x,
                                                         const _Float16* __restrict__ Bf,
                                                         float* __restrict__ out_w,
                                                         float* __restrict__ out_i) {
    __shared__ char BsB[4][8192];        // 4-deep ring of fragment-ordered W slabs (32 KB)
    __shared__ float ss[MT][NEXP + 3];   // scores for top-2 (17 KB)

    const int tid  = threadIdx.x;
    const int lane = tid & 63;
    const int wave = tid >> 6;
    const int wm   = wave >> 1;          // token half  (32 tok)
    const int wn   = wave & 1;           // expert half (32 exp)
    const int tb   = blockIdx.x * MT;

    // A: per-lane fragment row pointers; k-base (lane>>4)*8
    const float* xr0 = x + (size_t)(tb + wm * 32 +      (lane & 15)) * KDIM + ((lane >> 4) << 3);
    const float* xr1 = x + (size_t)(tb + wm * 32 + 16 + (lane & 15)) * KDIM + ((lane >> 4) << 3);
    const char* bsrc = reinterpret_cast<const char*>(Bf);

    f32x4 acc[2][2];
    #pragma unroll
    for (int m = 0; m < 2; ++m)
        #pragma unroll
        for (int n = 0; n < 2; ++n)
            acc[m][n] = (f32x4){0.f, 0.f, 0.f, 0.f};

    // depth-4 named A register ring (all indices compile-time constant)
    float4 As0[4], As1[4], As2[4], As3[4];

#define ISSUE_A(AS, c)                                                        \
    do {                                                                      \
        AS[0] = *reinterpret_cast<const float4*>(xr0 + (c) * KC);             \
        AS[1] = *reinterpret_cast<const float4*>(xr0 + (c) * KC + 4);         \
        AS[2] = *reinterpret_cast<const float4*>(xr1 + (c) * KC);             \
        AS[3] = *reinterpret_cast<const float4*>(xr1 + (c) * KC + 4);         \
    } while (0)

#define ISSUE_B(BUF, c)                                                       \
    do {                                                                      \
        int off0 = tid * 16;                                                  \
        __builtin_amdgcn_global_load_lds(                                     \
            (const GLOBAL_AS uint32_t*)(bsrc + (size_t)(c) * 8192 + off0),    \
            (LDS_AS uint32_t*)(&BsB[BUF][0] + off0), 16, 0, 0);               \
        __builtin_amdgcn_global_load_lds(                                     \
            (const GLOBAL_AS uint32_t*)(bsrc + (size_t)(c) * 8192 + off0 + 4096), \
            (LDS_AS uint32_t*)(&BsB[BUF][0] + off0 + 4096), 16, 0, 0);        \
    } while (0)

#define COMP(BUF, AS)                                                         \
    do {                                                                      \
        half8 bh[2], bl[2];                                                   \
        _Pragma("unroll")                                                     \
        for (int n = 0; n < 2; ++n) {                                         \
            int off = ((wn * 2 + n) * 64 + lane) * 16;                        \
            bh[n] = *reinterpret_cast<const half8*>(&BsB[BUF][off]);          \
            bl[n] = *reinterpret_cast<const half8*>(&BsB[BUF][off + 4096]);   \
        }                                                                     \
        _Pragma("unroll")                                                     \
        for (int m = 0; m < 2; ++m) {                                         \
            HL a = split8(AS[m * 2], AS[m * 2 + 1]);                          \
            _Pragma("unroll")                                                 \
            for (int n = 0; n < 2; ++n) {                                     \
                acc[m][n] = __builtin_amdgcn_mfma_f32_16x16x32_f16(a.h, bh[n], acc[m][n], 0, 0, 0); \
                acc[m][n] = __builtin_amdgcn_mfma_f32_16x16x32_f16(a.l, bh[n], acc[m][n], 0, 0, 0); \
                acc[m][n] = __builtin_amdgcn_mfma_f32_16x16x32_f16(a.h, bl[n], acc[m][n], 0, 0, 0); \
            }                                                                 \
        }                                                                     \
    } while (0)

    // prologue: 3 chunks in flight (18 VMEM ops)
    ISSUE_A(As0, 0); ISSUE_B(0, 0);
    ISSUE_A(As1, 1); ISSUE_B(1, 1);
    ISSUE_A(As2, 2); ISSUE_B(2, 2);

    // main: chunks 0..59; per chunk: wait set c (2 newer stay in flight),
    // barrier (no drain), issue c+3, compute c. Buf/set parity static.
    for (int q = 0; q < 15; ++q) {
        const int c = 4 * q;
        VMW12(); SBAR(); ISSUE_A(As3, c + 3); ISSUE_B(3, c + 3); COMP(0, As0);
        VMW12(); SBAR(); ISSUE_A(As0, c + 4); ISSUE_B(0, c + 4); COMP(1, As1);
        VMW12(); SBAR(); ISSUE_A(As1, c + 5); ISSUE_B(1, c + 5); COMP(2, As2);
        VMW12(); SBAR(); ISSUE_A(As2, c + 6); ISSUE_B(2, c + 6); COMP(3, As3);
    }
    // peeled tail: chunks 60..63
    VMW12(); SBAR(); ISSUE_A(As3, 63); ISSUE_B(3, 63); COMP(0, As0);  // c=60
    VMW12(); SBAR(); COMP(1, As1);                                    // c=61
    VMW6();  SBAR(); COMP(2, As2);                                    // c=62
    VMW0();  SBAR(); COMP(3, As3);                                    // c=63

    // ---- epilogue: top-2 per token ----
    #pragma unroll
    for (int m = 0; m < 2; ++m)
        #pragma unroll
        for (int n = 0; n < 2; ++n)
            #pragma unroll
            for (int r = 0; r < 4; ++r) {
                int tok = wm * 32 + m * 16 + (lane >> 4) * 4 + r;   // C/D: row=(lane>>4)*4+reg
                int e   = wn * 32 + n * 16 + (lane & 15);           //      col=lane&15 (m89)
                ss[tok][e] = acc[m][n][r];
            }
    __syncthreads();

    if (tid < MT) {
        const int t = tid;
        float m1 = -1e30f, m2 = -1e30f;
        int i1 = 0, i2 = 0;
        // strict '>' keeps the lower index on ties, matching jax.lax.top_k
        #pragma unroll
        for (int e = 0; e < NEXP; ++e) {
            float v = ss[t][e];
            if (v > m1) { m2 = m1; i2 = i1; m1 = v; i1 = e; }
            else if (v > m2) { m2 = v; i2 = e; }
        }
        const int gt = tb + t;
        out_w[gt * 2 + 0] = m1;
        out_w[gt * 2 + 1] = m2;
        out_i[gt * 2 + 0] = (float)i1;
        out_i[gt * 2 + 1] = (float)i2;
    }
#undef ISSUE_A
#undef ISSUE_B
#undef COMP
}

extern "C" void kernel_launch(void* const* d_in, const int* in_sizes, int n_in,
                              void* d_out, int out_size, void* d_ws, size_t ws_size,
                              hipStream_t stream) {
    const float* x = (const float*)d_in[0];   // [16384, 2048] f32
    const float* W = (const float*)d_in[1];   // [64, 2048]   f32
    float* out = (float*)d_out;               // [16384*2 weights][16384*2 indices]

    const int n_tokens = in_sizes[0] / KDIM;  // 16384
    _Float16* Bfp = (_Float16*)d_ws;          // 512 KB fragment-ordered W (hi+lo)

    hipLaunchKernelGGL(prep_w, dim3(64), dim3(256), 0, stream, W, Bfp);
    hipLaunchKernelGGL(router_kernel, dim3(n_tokens / MT), dim3(NTHR), 0, stream,
                       x, Bfp, out, out + 2 * (size_t)n_tokens);
}

// Round 12
// 51.099 us; speedup vs baseline: 1.1332x; 1.1332x over previous
//
#include <hip/hip_runtime.h>
#include <stdint.h>

#define KDIM 2048
#define NEXP 64
#define MT   32              // tokens per block  (R12: halved -> grid 512 = 2 blocks/CU)
#define KC   32              // k per chunk (one MFMA-K)
#define NCH  (KDIM / KC)     // 64 chunks
#define NTHR 256             // 4 waves: 2 token-halves x 2 expert-halves

typedef _Float16 half8 __attribute__((ext_vector_type(8)));
typedef __fp16  fp16x2 __attribute__((ext_vector_type(2)));
typedef float f32x4 __attribute__((ext_vector_type(4)));

// W[64][2048] f32 -> Wh/Wl [64][2048] f16 (scaled by 256, hi/lo split)
__global__ __launch_bounds__(256) void prep_w(const float* __restrict__ W,
                                              _Float16* __restrict__ Wh,
                                              _Float16* __restrict__ Wl) {
    int idx = blockIdx.x * 256 + threadIdx.x;   // 131072 total
    float y = W[idx] * 256.0f;
    _Float16 h = (_Float16)y;
    _Float16 l = (_Float16)(y - (float)h);
    Wh[idx] = h;
    Wl[idx] = l;
}

// swizzled byte offset within one [rows][64B] LDS tensor
__device__ __forceinline__ int swz(int row, int byte_in_row) {
    return ((row << 6) + byte_in_row) ^ ((row & 14) << 3);
}

__device__ __forceinline__ uint32_t pkrtz(float a, float b) {
    fp16x2 h = __builtin_amdgcn_cvt_pkrtz(a, b);
    return __builtin_bit_cast(uint32_t, h);
}
__device__ __forceinline__ float lo_f(uint32_t u) {
    fp16x2 h = __builtin_bit_cast(fp16x2, u);
    return (float)h[0];
}
__device__ __forceinline__ float hi_f(uint32_t u) {
    fp16x2 h = __builtin_bit_cast(fp16x2, u);
    return (float)h[1];
}

// counted waits + raw barrier (R8-proven): loads stay in flight across barriers
#define VMCNT3() do { asm volatile("s_waitcnt vmcnt(3)" ::: "memory"); \
                      __builtin_amdgcn_sched_barrier(0); } while (0)
#define VMCNT0() do { asm volatile("s_waitcnt vmcnt(0)" ::: "memory"); \
                      __builtin_amdgcn_sched_barrier(0); } while (0)
#define LGKM_BAR() do { asm volatile("s_waitcnt lgkmcnt(0)" ::: "memory"); \
                        __builtin_amdgcn_sched_barrier(0);                 \
                        __builtin_amdgcn_s_barrier();                      \
                        __builtin_amdgcn_sched_barrier(0); } while (0)

__global__ __launch_bounds__(NTHR) void router_kernel(const float* __restrict__ x,
                                                      const _Float16* __restrict__ Wh,
                                                      const _Float16* __restrict__ Wl,
                                                      float* __restrict__ out_w,
                                                      float* __restrict__ out_i) {
    __shared__ char AsB[2][2][2048];   // [buf][h/l] x-tiles: 32 tok x 32 k f16 (8 KB)
    __shared__ char BsB[2][2][4096];   // [buf][h/l] w-tiles: 64 exp x 32 k f16 (16 KB)
    __shared__ float ss[MT][67];       // scores for top-2 (8.6 KB) -> 32.6 KB total

    const int tid  = threadIdx.x;
    const int lane = tid & 63;
    const int wave = tid >> 6;
    const int wm   = wave >> 1;        // token half  (16 tok)
    const int wn   = wave & 1;         // expert half (32 exp)
    const int tb   = blockIdx.x * MT;

    // ---- staging coords ----
    const int xrow = tid >> 3;                  // 0..31
    const int xseg = tid & 7;
    const float* xsrc = x + (size_t)(tb + xrow) * KDIM + xseg * 4;
    const int xoff = swz(xrow, xseg * 8);
    const int wrr = tid >> 2;                   // expert row 0..63
    const int wss = tid & 3;                    // 16B segment
    const _Float16* wsrc0 = Wh + (size_t)wrr * KDIM + wss * 8;
    const _Float16* wsrc1 = Wl + (size_t)wrr * KDIM + wss * 8;
    const int woff = swz(wrr, wss * 16);

    // ---- compute-side read offsets ----
    const int kb = lane >> 4;
    const int ra0 = wm * 16 + (lane & 15);
    const int rb0 = wn * 32 + (lane & 15);
    const int aoff  = swz(ra0,      kb * 16);
    const int boff0 = swz(rb0,      kb * 16);
    const int boff1 = swz(rb0 + 16, kb * 16);

    f32x4 acc[2];
    acc[0] = (f32x4){0.f, 0.f, 0.f, 0.f};
    acc[1] = (f32x4){0.f, 0.f, 0.f, 0.f};

    // two NAMED register prefetch sets
    float4 Ax;  half8 Aw0, Aw1;   // set A
    float4 Bx;  half8 Bw0, Bw1;   // set B

#define LOADM(X0, W0, W1, c)                                               \
    do {                                                                   \
        X0 = *reinterpret_cast<const float4*>(xsrc + (c) * KC);            \
        W0 = *reinterpret_cast<const half8*>(wsrc0 + (c) * KC);            \
        W1 = *reinterpret_cast<const half8*>(wsrc1 + (c) * KC);            \
    } while (0)

    auto STORE = [&](int b, float4 v, half8 w0, half8 w1) {
        float y0 = v.x * 256.0f, y1 = v.y * 256.0f, y2 = v.z * 256.0f, y3 = v.w * 256.0f;
        uint32_t h01 = pkrtz(y0, y1);
        uint32_t h23 = pkrtz(y2, y3);
        float l0 = y0 - lo_f(h01), l1 = y1 - hi_f(h01);
        float l2 = y2 - lo_f(h23), l3 = y3 - hi_f(h23);
        uint32_t q01 = pkrtz(l0, l1);
        uint32_t q23 = pkrtz(l2, l3);
        uint2 hv, lv;
        hv.x = h01; hv.y = h23;
        lv.x = q01; lv.y = q23;
        *reinterpret_cast<uint2*>(&AsB[b][0][0] + xoff) = hv;
        *reinterpret_cast<uint2*>(&AsB[b][1][0] + xoff) = lv;
        *reinterpret_cast<half8*>(&BsB[b][0][0] + woff) = w0;
        *reinterpret_cast<half8*>(&BsB[b][1][0] + woff) = w1;
    };

    auto COMPUTE = [&](int b) {
        half8 ah, al, bh[2], bl[2];
        ah = *reinterpret_cast<const half8*>(&AsB[b][0][0] + aoff);
        al = *reinterpret_cast<const half8*>(&AsB[b][1][0] + aoff);
        bh[0] = *reinterpret_cast<const half8*>(&BsB[b][0][0] + boff0);
        bh[1] = *reinterpret_cast<const half8*>(&BsB[b][0][0] + boff1);
        bl[0] = *reinterpret_cast<const half8*>(&BsB[b][1][0] + boff0);
        bl[1] = *reinterpret_cast<const half8*>(&BsB[b][1][0] + boff1);
        #pragma unroll
        for (int n = 0; n < 2; ++n) {
            acc[n] = __builtin_amdgcn_mfma_f32_16x16x32_f16(ah, bh[n], acc[n], 0, 0, 0);
            acc[n] = __builtin_amdgcn_mfma_f32_16x16x32_f16(al, bh[n], acc[n], 0, 0, 0);
            acc[n] = __builtin_amdgcn_mfma_f32_16x16x32_f16(ah, bl[n], acc[n], 0, 0, 0);
        }
    };

    // ---- prologue ----
    LOADM(Ax, Aw0, Aw1, 0);   // chunk 0 -> set A
    LOADM(Bx, Bw0, Bw1, 1);   // chunk 1 -> set B   (6 loads in flight)
    VMCNT3();                 // set A complete, set B still flying
    STORE(0, Ax, Aw0, Aw1);   // buf0 <- chunk 0
    LGKM_BAR();

    // ---- main loop: chunks 0..61, unrolled x2 for static buffer/set parity ----
    for (int q = 0; q < 31; ++q) {
        COMPUTE(0);
        LOADM(Ax, Aw0, Aw1, 2 * q + 2);
        VMCNT3();                    // chunk 2q+1 (set B) landed; 2q+2 still flying
        STORE(1, Bx, Bw0, Bw1);
        LGKM_BAR();
        COMPUTE(1);
        LOADM(Bx, Bw0, Bw1, 2 * q + 3);
        VMCNT3();
        STORE(0, Ax, Aw0, Aw1);
        LGKM_BAR();
    }
    // ---- tail: chunk 62 (buf 0), store chunk 63 (set B); chunk 63 (buf 1) ----
    COMPUTE(0);
    VMCNT0();
    STORE(1, Bx, Bw0, Bw1);
    LGKM_BAR();
    COMPUTE(1);

    // ---- epilogue: scale back (exact 2^-16) and top-2 per token ----
    const float sc = 1.0f / 65536.0f;
    #pragma unroll
    for (int n = 0; n < 2; ++n)
        #pragma unroll
        for (int r = 0; r < 4; ++r) {
            int tok = wm * 16 + (lane >> 4) * 4 + r;     // C/D: row=(lane>>4)*4+reg
            int e   = wn * 32 + n * 16 + (lane & 15);    //      col=lane&15  (m89)
            ss[tok][e] = acc[n][r] * sc;
        }
    __syncthreads();

    if (tid < MT) {
        const int t = tid;
        float m1 = -1e30f, m2 = -1e30f;
        int i1 = 0, i2 = 0;
        // strict '>' keeps the lower index on ties, matching jax.lax.top_k
        #pragma unroll
        for (int e = 0; e < NEXP; ++e) {
            float v = ss[t][e];
            if (v > m1) { m2 = m1; i2 = i1; m1 = v; i1 = e; }
            else if (v > m2) { m2 = v; i2 = e; }
        }
        const int gt = tb + t;
        out_w[gt * 2 + 0] = m1;
        out_w[gt * 2 + 1] = m2;
        out_i[gt * 2 + 0] = (float)i1;
        out_i[gt * 2 + 1] = (float)i2;
    }
#undef LOADM
}

extern "C" void kernel_launch(void* const* d_in, const int* in_sizes, int n_in,
                              void* d_out, int out_size, void* d_ws, size_t ws_size,
                              hipStream_t stream) {
    const float* x = (const float*)d_in[0];   // [16384, 2048] f32
    const float* W = (const float*)d_in[1];   // [64, 2048]   f32
    float* out = (float*)d_out;               // [16384*2 weights][16384*2 indices]

    const int n_tokens = in_sizes[0] / KDIM;  // 16384
    _Float16* Whp = (_Float16*)d_ws;          // 256 KB
    _Float16* Wlp = Whp + (size_t)NEXP * KDIM; // +256 KB

    hipLaunchKernelGGL(prep_w, dim3((NEXP * KDIM) / 256), dim3(256), 0, stream, W, Whp, Wlp);
    hipLaunchKernelGGL(router_kernel, dim3(n_tokens / MT), dim3(NTHR), 0, stream,
                       x, Whp, Wlp, out, out + 2 * (size_t)n_tokens);
}

// Round 13
// 40.097 us; speedup vs baseline: 1.4441x; 1.2744x over previous
//
#include <hip/hip_runtime.h>
#include <stdint.h>

#define KDIM 2048
#define NEXP 64
#define MT   64              // tokens per block
#define KC   32              // k per chunk (one MFMA-K)
#define NCH2 32              // chunks per K-half block
#define NTHR 256             // 4 waves: 2 token-halves x 2 expert-halves
#define NTOK 16384

typedef _Float16 half8 __attribute__((ext_vector_type(8)));
typedef __fp16  fp16x2 __attribute__((ext_vector_type(2)));
typedef float f32x4 __attribute__((ext_vector_type(4)));

// W[64][2048] f32 -> Wh/Wl [64][2048] f16 (scaled by 256, hi/lo split)
__global__ __launch_bounds__(256) void prep_w(const float* __restrict__ W,
                                              _Float16* __restrict__ Wh,
                                              _Float16* __restrict__ Wl) {
    int idx = blockIdx.x * 256 + threadIdx.x;   // 131072 total
    float y = W[idx] * 256.0f;
    _Float16 h = (_Float16)y;
    _Float16 l = (_Float16)(y - (float)h);
    Wh[idx] = h;
    Wl[idx] = l;
}

// swizzled byte offset within one [64 rows][64B] LDS tensor
__device__ __forceinline__ int swz(int row, int byte_in_row) {
    return ((row << 6) + byte_in_row) ^ ((row & 14) << 3);
}

__device__ __forceinline__ uint32_t pkrtz(float a, float b) {
    fp16x2 h = __builtin_amdgcn_cvt_pkrtz(a, b);
    return __builtin_bit_cast(uint32_t, h);
}
__device__ __forceinline__ float lo_f(uint32_t u) {
    fp16x2 h = __builtin_bit_cast(fp16x2, u);
    return (float)h[0];
}
__device__ __forceinline__ float hi_f(uint32_t u) {
    fp16x2 h = __builtin_bit_cast(fp16x2, u);
    return (float)h[1];
}

// counted waits + raw barrier (R8-proven): loads stay in flight across barriers
#define VMCNT4() do { asm volatile("s_waitcnt vmcnt(4)" ::: "memory"); \
                      __builtin_amdgcn_sched_barrier(0); } while (0)
#define VMCNT0() do { asm volatile("s_waitcnt vmcnt(0)" ::: "memory"); \
                      __builtin_amdgcn_sched_barrier(0); } while (0)
#define LGKM_BAR() do { asm volatile("s_waitcnt lgkmcnt(0)" ::: "memory"); \
                        __builtin_amdgcn_sched_barrier(0);                 \
                        __builtin_amdgcn_s_barrier();                      \
                        __builtin_amdgcn_sched_barrier(0); } while (0)

// Split-K router: block (tg, kh) computes partial scores over k in [kh*1024, kh*1024+1024)
__global__ __launch_bounds__(NTHR) void router_kernel(const float* __restrict__ x,
                                                      const _Float16* __restrict__ Wh,
                                                      const _Float16* __restrict__ Wl,
                                                      float* __restrict__ partials) {
    __shared__ char AsB[2][2][4096];   // [buf][h/l] x-tiles: 64 tok x 32 k f16
    __shared__ char BsB[2][2][4096];   // [buf][h/l] w-tiles: 64 exp x 32 k f16  (32 KB)

    const int tid  = threadIdx.x;
    const int lane = tid & 63;
    const int wave = tid >> 6;
    const int wm   = wave >> 1;        // token half  (32 tok)
    const int wn   = wave & 1;         // expert half (32 exp)
    const int kh   = blockIdx.x & 1;   // K-half
    const int tb   = (blockIdx.x >> 1) * MT;
    const int kb0  = kh * (KDIM / 2);  // k offset of this half

    // ---- staging coords (identical to R8, shifted by kb0) ----
    const int xrow0 = tid >> 3;                 // 0..31
    const int xseg  = tid & 7;
    const float* xsrc0 = x + (size_t)(tb + xrow0) * KDIM + kb0 + xseg * 4;
    const float* xsrc1 = x + (size_t)(tb + xrow0 + 32) * KDIM + kb0 + xseg * 4;
    const int xoff0 = swz(xrow0, xseg * 8);
    const int xoff1 = swz(xrow0 + 32, xseg * 8);
    const int wrr = tid >> 2;                   // expert row
    const int wss = tid & 3;                    // 16B segment
    const _Float16* wsrc0 = Wh + (size_t)wrr * KDIM + kb0 + wss * 8;
    const _Float16* wsrc1 = Wl + (size_t)wrr * KDIM + kb0 + wss * 8;
    const int woff = swz(wrr, wss * 16);

    // ---- compute-side read offsets ----
    const int kb = lane >> 4;
    const int ra0 = wm * 32 + (lane & 15);
    const int rb0 = wn * 32 + (lane & 15);
    const int aoff0 = swz(ra0,      kb * 16);
    const int aoff1 = swz(ra0 + 16, kb * 16);
    const int boff0 = swz(rb0,      kb * 16);
    const int boff1 = swz(rb0 + 16, kb * 16);

    f32x4 acc[2][2];
    #pragma unroll
    for (int i = 0; i < 2; ++i)
        #pragma unroll
        for (int j = 0; j < 2; ++j)
            acc[i][j] = (f32x4){0.f, 0.f, 0.f, 0.f};

    float4 Ax0, Ax1;  half8 Aw0, Aw1;   // named set A
    float4 Bx0, Bx1;  half8 Bw0, Bw1;   // named set B

#define LOADM(X0, X1, W0, W1, c)                                           \
    do {                                                                   \
        X0 = *reinterpret_cast<const float4*>(xsrc0 + (c) * KC);           \
        X1 = *reinterpret_cast<const float4*>(xsrc1 + (c) * KC);           \
        W0 = *reinterpret_cast<const half8*>(wsrc0 + (c) * KC);            \
        W1 = *reinterpret_cast<const half8*>(wsrc1 + (c) * KC);            \
    } while (0)

    auto STORE = [&](int b, float4 v0, float4 v1, half8 w0, half8 w1) {
        #pragma unroll
        for (int i = 0; i < 2; ++i) {
            float4 v = i ? v1 : v0;
            float y0 = v.x * 256.0f, y1 = v.y * 256.0f, y2 = v.z * 256.0f, y3 = v.w * 256.0f;
            uint32_t h01 = pkrtz(y0, y1);
            uint32_t h23 = pkrtz(y2, y3);
            float l0 = y0 - lo_f(h01), l1 = y1 - hi_f(h01);
            float l2 = y2 - lo_f(h23), l3 = y3 - hi_f(h23);
            uint32_t q01 = pkrtz(l0, l1);
            uint32_t q23 = pkrtz(l2, l3);
            uint2 hv, lv;
            hv.x = h01; hv.y = h23;
            lv.x = q01; lv.y = q23;
            int off = i ? xoff1 : xoff0;
            *reinterpret_cast<uint2*>(&AsB[b][0][0] + off) = hv;
            *reinterpret_cast<uint2*>(&AsB[b][1][0] + off) = lv;
        }
        *reinterpret_cast<half8*>(&BsB[b][0][0] + woff) = w0;
        *reinterpret_cast<half8*>(&BsB[b][1][0] + woff) = w1;
    };

    auto COMPUTE = [&](int b) {
        half8 ah[2], al[2], bh[2], bl[2];
        ah[0] = *reinterpret_cast<const half8*>(&AsB[b][0][0] + aoff0);
        ah[1] = *reinterpret_cast<const half8*>(&AsB[b][0][0] + aoff1);
        al[0] = *reinterpret_cast<const half8*>(&AsB[b][1][0] + aoff0);
        al[1] = *reinterpret_cast<const half8*>(&AsB[b][1][0] + aoff1);
        bh[0] = *reinterpret_cast<const half8*>(&BsB[b][0][0] + boff0);
        bh[1] = *reinterpret_cast<const half8*>(&BsB[b][0][0] + boff1);
        bl[0] = *reinterpret_cast<const half8*>(&BsB[b][1][0] + boff0);
        bl[1] = *reinterpret_cast<const half8*>(&BsB[b][1][0] + boff1);
        #pragma unroll
        for (int m = 0; m < 2; ++m)
            #pragma unroll
            for (int n = 0; n < 2; ++n) {
                acc[m][n] = __builtin_amdgcn_mfma_f32_16x16x32_f16(ah[m], bh[n], acc[m][n], 0, 0, 0);
                acc[m][n] = __builtin_amdgcn_mfma_f32_16x16x32_f16(al[m], bh[n], acc[m][n], 0, 0, 0);
                acc[m][n] = __builtin_amdgcn_mfma_f32_16x16x32_f16(ah[m], bl[n], acc[m][n], 0, 0, 0);
            }
    };

    // ---- prologue ----
    LOADM(Ax0, Ax1, Aw0, Aw1, 0);
    LOADM(Bx0, Bx1, Bw0, Bw1, 1);
    VMCNT4();
    STORE(0, Ax0, Ax1, Aw0, Aw1);
    LGKM_BAR();

    // ---- main loop: chunks 0..29 ----
    for (int q = 0; q < 15; ++q) {
        COMPUTE(0);
        LOADM(Ax0, Ax1, Aw0, Aw1, 2 * q + 2);
        VMCNT4();
        STORE(1, Bx0, Bx1, Bw0, Bw1);
        LGKM_BAR();
        COMPUTE(1);
        LOADM(Bx0, Bx1, Bw0, Bw1, 2 * q + 3);
        VMCNT4();
        STORE(0, Ax0, Ax1, Aw0, Aw1);
        LGKM_BAR();
    }
    // ---- tail: chunks 30, 31 ----
    COMPUTE(0);
    VMCNT0();
    STORE(1, Bx0, Bx1, Bw0, Bw1);
    LGKM_BAR();
    COMPUTE(1);

    // ---- epilogue: write partial scores (scaled back by exact 2^-16) ----
    const float sc = 1.0f / 65536.0f;
    float* pbase = partials + (size_t)kh * NTOK * NEXP;
    #pragma unroll
    for (int m = 0; m < 2; ++m)
        #pragma unroll
        for (int n = 0; n < 2; ++n)
            #pragma unroll
            for (int r = 0; r < 4; ++r) {
                int tok = wm * 32 + m * 16 + (lane >> 4) * 4 + r;   // C/D: row=(lane>>4)*4+reg
                int e   = wn * 32 + n * 16 + (lane & 15);           //      col=lane&15  (m89)
                pbase[(size_t)(tb + tok) * NEXP + e] = acc[m][n][r] * sc;
            }
#undef LOADM
}

// sum the two K-half partials and take top-2 per token
__global__ __launch_bounds__(256) void reduce_kernel(const float* __restrict__ partials,
                                                     float* __restrict__ out_w,
                                                     float* __restrict__ out_i) {
    const int t = blockIdx.x * 256 + threadIdx.x;   // token, grid 64 x 256
    const float4* p0 = reinterpret_cast<const float4*>(partials + (size_t)t * NEXP);
    const float4* p1 = reinterpret_cast<const float4*>(partials + (size_t)NTOK * NEXP + (size_t)t * NEXP);
    float s[NEXP];
    #pragma unroll
    for (int j = 0; j < NEXP / 4; ++j) {
        float4 a = p0[j];
        float4 b = p1[j];
        s[4 * j + 0] = a.x + b.x;
        s[4 * j + 1] = a.y + b.y;
        s[4 * j + 2] = a.z + b.z;
        s[4 * j + 3] = a.w + b.w;
    }
    float m1 = -1e30f, m2 = -1e30f;
    int i1 = 0, i2 = 0;
    // strict '>' keeps the lower index on ties, matching jax.lax.top_k
    #pragma unroll
    for (int e = 0; e < NEXP; ++e) {
        float v = s[e];
        if (v > m1) { m2 = m1; i2 = i1; m1 = v; i1 = e; }
        else if (v > m2) { m2 = v; i2 = e; }
    }
    out_w[t * 2 + 0] = m1;
    out_w[t * 2 + 1] = m2;
    out_i[t * 2 + 0] = (float)i1;
    out_i[t * 2 + 1] = (float)i2;
}

extern "C" void kernel_launch(void* const* d_in, const int* in_sizes, int n_in,
                              void* d_out, int out_size, void* d_ws, size_t ws_size,
                              hipStream_t stream) {
    const float* x = (const float*)d_in[0];   // [16384, 2048] f32
    const float* W = (const float*)d_in[1];   // [64, 2048]   f32
    float* out = (float*)d_out;               // [16384*2 weights][16384*2 indices]

    const int n_tokens = in_sizes[0] / KDIM;  // 16384
    _Float16* Whp = (_Float16*)d_ws;                    // 256 KB
    _Float16* Wlp = Whp + (size_t)NEXP * KDIM;          // +256 KB
    float* partials = (float*)(Wlp + (size_t)NEXP * KDIM);  // 2 x 4 MB

    hipLaunchKernelGGL(prep_w, dim3((NEXP * KDIM) / 256), dim3(256), 0, stream, W, Whp, Wlp);
    hipLaunchKernelGGL(router_kernel, dim3((n_tokens / MT) * 2), dim3(NTHR), 0, stream,
                       x, Whp, Wlp, partials);
    hipLaunchKernelGGL(reduce_kernel, dim3(n_tokens / 256), dim3(256), 0, stream,
                       partials, out, out + 2 * (size_t)n_tokens);
}

// Round 14
// 35.060 us; speedup vs baseline: 1.6516x; 1.1437x over previous
//
#include <hip/hip_runtime.h>
#include <stdint.h>

#define KDIM 2048
#define NEXP 64
#define MT   64              // tokens per block
#define KC   32              // k per chunk (one MFMA-K)
#define NTHR 256             // 4 waves: 2 token-halves x 2 expert-halves
#define NTOK 16384

typedef _Float16 half8 __attribute__((ext_vector_type(8)));
typedef __fp16  fp16x2 __attribute__((ext_vector_type(2)));
typedef float f32x4 __attribute__((ext_vector_type(4)));

// swizzled byte offset within one [64 rows][64B] LDS tensor
__device__ __forceinline__ int swz(int row, int byte_in_row) {
    return ((row << 6) + byte_in_row) ^ ((row & 14) << 3);
}

__device__ __forceinline__ uint32_t pkrtz(float a, float b) {
    fp16x2 h = __builtin_amdgcn_cvt_pkrtz(a, b);
    return __builtin_bit_cast(uint32_t, h);
}

// truncate-split 4 f32 -> (4 f16 hi, 4 f16 lo) as two uint2 (R7/R9-proven numerics)
__device__ __forceinline__ void split4(float4 v, uint2* hv, uint2* lv) {
    float y[4] = {v.x, v.y, v.z, v.w};
    uint32_t hw[2], lw[2];
    #pragma unroll
    for (int i = 0; i < 2; ++i) {
        float y0 = y[2 * i], y1 = y[2 * i + 1];
        float h0 = __builtin_bit_cast(float, __builtin_bit_cast(uint32_t, y0) & 0xFFFFE000u);
        float h1 = __builtin_bit_cast(float, __builtin_bit_cast(uint32_t, y1) & 0xFFFFE000u);
        hw[i] = pkrtz(h0, h1);
        lw[i] = pkrtz(y0 - h0, y1 - h1);
    }
    hv->x = hw[0]; hv->y = hw[1];
    lv->x = lw[0]; lv->y = lw[1];
}

// counted waits + raw barrier (R8-proven): loads stay in flight across barriers
#define VMCNT4() do { asm volatile("s_waitcnt vmcnt(4)" ::: "memory"); \
                      __builtin_amdgcn_sched_barrier(0); } while (0)
#define VMCNT0() do { asm volatile("s_waitcnt vmcnt(0)" ::: "memory"); \
                      __builtin_amdgcn_sched_barrier(0); } while (0)
#define LGKM_BAR() do { asm volatile("s_waitcnt lgkmcnt(0)" ::: "memory"); \
                        __builtin_amdgcn_sched_barrier(0);                 \
                        __builtin_amdgcn_s_barrier();                      \
                        __builtin_amdgcn_sched_barrier(0); } while (0)

// Split-K router with on-the-fly W split: block (tg, kh) does k in [kh*1024, +1024)
__global__ __launch_bounds__(NTHR) void router_kernel(const float* __restrict__ x,
                                                      const float* __restrict__ W,
                                                      float* __restrict__ partials) {
    __shared__ char AsB[2][2][4096];   // [buf][h/l] x-tiles: 64 tok x 32 k f16
    __shared__ char BsB[2][2][4096];   // [buf][h/l] w-tiles: 64 exp x 32 k f16  (32 KB)

    const int tid  = threadIdx.x;
    const int lane = tid & 63;
    const int wave = tid >> 6;
    const int wm   = wave >> 1;        // token half  (32 tok)
    const int wn   = wave & 1;         // expert half (32 exp)
    const int kh   = blockIdx.x & 1;   // K-half
    const int tb   = (blockIdx.x >> 1) * MT;
    const int kb0  = kh * (KDIM / 2);  // k offset of this half

    // ---- staging coords ----
    const int xrow0 = tid >> 3;                 // 0..31
    const int xseg  = tid & 7;
    const float* xsrc0 = x + (size_t)(tb + xrow0) * KDIM + kb0 + xseg * 4;
    const float* xsrc1 = x + (size_t)(tb + xrow0 + 32) * KDIM + kb0 + xseg * 4;
    const int xoff0 = swz(xrow0, xseg * 8);
    const int xoff1 = swz(xrow0 + 32, xseg * 8);
    const int wrr = tid >> 2;                   // expert row 0..63
    const int wss = tid & 3;                    // 8-float segment
    const float* wsrc = W + (size_t)wrr * KDIM + kb0 + wss * 8;
    const int woff = swz(wrr, wss * 16);

    // ---- compute-side read offsets ----
    const int kb = lane >> 4;
    const int ra0 = wm * 32 + (lane & 15);
    const int rb0 = wn * 32 + (lane & 15);
    const int aoff0 = swz(ra0,      kb * 16);
    const int aoff1 = swz(ra0 + 16, kb * 16);
    const int boff0 = swz(rb0,      kb * 16);
    const int boff1 = swz(rb0 + 16, kb * 16);

    f32x4 acc[2][2];
    #pragma unroll
    for (int i = 0; i < 2; ++i)
        #pragma unroll
        for (int j = 0; j < 2; ++j)
            acc[i][j] = (f32x4){0.f, 0.f, 0.f, 0.f};

    // named register prefetch sets: x rows + raw f32 W segment (2 float4)
    float4 Ax0, Ax1, Aw0, Aw1;   // set A
    float4 Bx0, Bx1, Bw0, Bw1;   // set B

#define LOADM(X0, X1, W0, W1, c)                                           \
    do {                                                                   \
        X0 = *reinterpret_cast<const float4*>(xsrc0 + (c) * KC);           \
        X1 = *reinterpret_cast<const float4*>(xsrc1 + (c) * KC);           \
        W0 = *reinterpret_cast<const float4*>(wsrc + (c) * KC);            \
        W1 = *reinterpret_cast<const float4*>(wsrc + (c) * KC + 4);        \
    } while (0)

    auto STORE = [&](int b, float4 v0, float4 v1, float4 w0, float4 w1) {
        uint2 hv, lv;
        split4(v0, &hv, &lv);
        *reinterpret_cast<uint2*>(&AsB[b][0][0] + xoff0) = hv;
        *reinterpret_cast<uint2*>(&AsB[b][1][0] + xoff0) = lv;
        split4(v1, &hv, &lv);
        *reinterpret_cast<uint2*>(&AsB[b][0][0] + xoff1) = hv;
        *reinterpret_cast<uint2*>(&AsB[b][1][0] + xoff1) = lv;
        uint2 h0, l0, h1, l1;
        split4(w0, &h0, &l0);
        split4(w1, &h1, &l1);
        uint4 wh = {h0.x, h0.y, h1.x, h1.y};
        uint4 wl = {l0.x, l0.y, l1.x, l1.y};
        *reinterpret_cast<uint4*>(&BsB[b][0][0] + woff) = wh;
        *reinterpret_cast<uint4*>(&BsB[b][1][0] + woff) = wl;
    };

    auto COMPUTE = [&](int b) {
        half8 ah[2], al[2], bh[2], bl[2];
        ah[0] = *reinterpret_cast<const half8*>(&AsB[b][0][0] + aoff0);
        ah[1] = *reinterpret_cast<const half8*>(&AsB[b][0][0] + aoff1);
        al[0] = *reinterpret_cast<const half8*>(&AsB[b][1][0] + aoff0);
        al[1] = *reinterpret_cast<const half8*>(&AsB[b][1][0] + aoff1);
        bh[0] = *reinterpret_cast<const half8*>(&BsB[b][0][0] + boff0);
        bh[1] = *reinterpret_cast<const half8*>(&BsB[b][0][0] + boff1);
        bl[0] = *reinterpret_cast<const half8*>(&BsB[b][1][0] + boff0);
        bl[1] = *reinterpret_cast<const half8*>(&BsB[b][1][0] + boff1);
        #pragma unroll
        for (int m = 0; m < 2; ++m)
            #pragma unroll
            for (int n = 0; n < 2; ++n) {
                acc[m][n] = __builtin_amdgcn_mfma_f32_16x16x32_f16(ah[m], bh[n], acc[m][n], 0, 0, 0);
                acc[m][n] = __builtin_amdgcn_mfma_f32_16x16x32_f16(al[m], bh[n], acc[m][n], 0, 0, 0);
                acc[m][n] = __builtin_amdgcn_mfma_f32_16x16x32_f16(ah[m], bl[n], acc[m][n], 0, 0, 0);
            }
    };

    // ---- prologue ----
    LOADM(Ax0, Ax1, Aw0, Aw1, 0);
    LOADM(Bx0, Bx1, Bw0, Bw1, 1);
    VMCNT4();
    STORE(0, Ax0, Ax1, Aw0, Aw1);
    LGKM_BAR();

    // ---- main loop: chunks 0..29 ----
    for (int q = 0; q < 15; ++q) {
        COMPUTE(0);
        LOADM(Ax0, Ax1, Aw0, Aw1, 2 * q + 2);
        VMCNT4();
        STORE(1, Bx0, Bx1, Bw0, Bw1);
        LGKM_BAR();
        COMPUTE(1);
        LOADM(Bx0, Bx1, Bw0, Bw1, 2 * q + 3);
        VMCNT4();
        STORE(0, Ax0, Ax1, Aw0, Aw1);
        LGKM_BAR();
    }
    // ---- tail: chunks 30, 31 ----
    COMPUTE(0);
    VMCNT0();
    STORE(1, Bx0, Bx1, Bw0, Bw1);
    LGKM_BAR();
    COMPUTE(1);

    // ---- epilogue: write partial scores (truncate-split => no rescale) ----
    float* pbase = partials + (size_t)kh * NTOK * NEXP;
    #pragma unroll
    for (int m = 0; m < 2; ++m)
        #pragma unroll
        for (int n = 0; n < 2; ++n)
            #pragma unroll
            for (int r = 0; r < 4; ++r) {
                int tok = wm * 32 + m * 16 + (lane >> 4) * 4 + r;   // C/D: row=(lane>>4)*4+reg
                int e   = wn * 32 + n * 16 + (lane & 15);           //      col=lane&15  (m89)
                pbase[(size_t)(tb + tok) * NEXP + e] = acc[m][n][r];
            }
#undef LOADM
}

// sum the two K-half partials and take top-2 per token
__global__ __launch_bounds__(256) void reduce_kernel(const float* __restrict__ partials,
                                                     float* __restrict__ out_w,
                                                     float* __restrict__ out_i) {
    const int t = blockIdx.x * 256 + threadIdx.x;   // token
    const float4* p0 = reinterpret_cast<const float4*>(partials + (size_t)t * NEXP);
    const float4* p1 = reinterpret_cast<const float4*>(partials + (size_t)NTOK * NEXP + (size_t)t * NEXP);
    float s[NEXP];
    #pragma unroll
    for (int j = 0; j < NEXP / 4; ++j) {
        float4 a = p0[j];
        float4 b = p1[j];
        s[4 * j + 0] = a.x + b.x;
        s[4 * j + 1] = a.y + b.y;
        s[4 * j + 2] = a.z + b.z;
        s[4 * j + 3] = a.w + b.w;
    }
    float m1 = -1e30f, m2 = -1e30f;
    int i1 = 0, i2 = 0;
    // strict '>' keeps the lower index on ties, matching jax.lax.top_k
    #pragma unroll
    for (int e = 0; e < NEXP; ++e) {
        float v = s[e];
        if (v > m1) { m2 = m1; i2 = i1; m1 = v; i1 = e; }
        else if (v > m2) { m2 = v; i2 = e; }
    }
    out_w[t * 2 + 0] = m1;
    out_w[t * 2 + 1] = m2;
    out_i[t * 2 + 0] = (float)i1;
    out_i[t * 2 + 1] = (float)i2;
}

extern "C" void kernel_launch(void* const* d_in, const int* in_sizes, int n_in,
                              void* d_out, int out_size, void* d_ws, size_t ws_size,
                              hipStream_t stream) {
    const float* x = (const float*)d_in[0];   // [16384, 2048] f32
    const float* W = (const float*)d_in[1];   // [64, 2048]   f32
    float* out = (float*)d_out;               // [16384*2 weights][16384*2 indices]

    const int n_tokens = in_sizes[0] / KDIM;  // 16384
    float* partials = (float*)d_ws;           // 2 x 4 MB

    hipLaunchKernelGGL(router_kernel, dim3((n_tokens / MT) * 2), dim3(NTHR), 0, stream,
                       x, W, partials);
    hipLaunchKernelGGL(reduce_kernel, dim3(n_tokens / 256), dim3(256), 0, stream,
                       partials, out, out + 2 * (size_t)n_tokens);
}